// Round 1
// baseline (205.618 us; speedup 1.0000x reference)
//
#include <hip/hip_runtime.h>

#define G    128
#define G3   (G * G * G)          // 2097152
#define TDIM 32
#define NTOT (TDIM * G3)          // 67108864
#define NBYTES_OUT (NTOT / 8)     // 8388608
#define DECAY 0.95f
#define DTH   0.01f
#define NBLK1 (TDIM * 512)        // 16384 blocks, each = one (t, 16^3 cube)

// extract every 3rd bit starting at bit 0 (inverse of instant-ngp expand_bits)
__device__ __forceinline__ unsigned compact3(unsigned v) {
    v &= 0x49249249u;
    v = (v | (v >> 2))  & 0xC30C30C3u;
    v = (v | (v >> 4))  & 0x0F00F00Fu;
    v = (v | (v >> 8))  & 0xFF0000FFu;
    v = (v | (v >> 16)) & 0x000003FFu;
    return v;
}

// Pass 1: per element (morton index j, time t):
//   s = sigmas[t, demorton(j)];  v = density[t, j]
//   r = (v>=0 && s>=0) ? max(v*DECAY, s) : v
//   write r; write bitfield byte assuming thresh==0.01f; accumulate clip-sum.
__global__ __launch_bounds__(1024) void
pass1(const float* __restrict__ dg, const float* __restrict__ sg,
      float* __restrict__ out_grid, float* __restrict__ out_bits,
      float* __restrict__ partials)
{
    const int blk  = blockIdx.x;        // t*512 + cube
    const int t    = blk >> 9;
    const int base = t * G3;
    const int j    = ((blk & 511) << 12) + (threadIdx.x << 2); // 4 consecutive morton idx

    const float* __restrict__ dgt = dg + base;
    const float* __restrict__ sgt = sg + base;

    // demorton of j (low 2 bits of j are zero -> x0=y0=0)
    const unsigned x = compact3((unsigned)j);
    const unsigned y = compact3((unsigned)j >> 1);
    const unsigned z = compact3((unsigned)j >> 2);
    const int ib = (int)((x << 14) | (y << 7) | z);

    // gather sigmas: j+1 -> x+1 (+16384), j+2 -> y+1 (+128), j+3 -> both
    const float s0 = sgt[ib];
    const float s1 = sgt[ib + 16384];
    const float s2 = sgt[ib + 128];
    const float s3 = sgt[ib + 16512];

    const float4 v = *reinterpret_cast<const float4*>(dgt + j);

    float4 r;
    r.x = (v.x >= 0.f && s0 >= 0.f) ? fmaxf(v.x * DECAY, s0) : v.x;
    r.y = (v.y >= 0.f && s1 >= 0.f) ? fmaxf(v.y * DECAY, s1) : v.y;
    r.z = (v.z >= 0.f && s2 >= 0.f) ? fmaxf(v.z * DECAY, s2) : v.z;
    r.w = (v.w >= 0.f && s3 >= 0.f) ? fmaxf(v.w * DECAY, s3) : v.w;

    *reinterpret_cast<float4*>(out_grid + base + j) = r;

    float lsum = fmaxf(r.x, 0.f) + fmaxf(r.y, 0.f) + fmaxf(r.z, 0.f) + fmaxf(r.w, 0.f);

    // bitfield assuming thresh == DTH (fixed up later iff mean < DTH)
    int nib = (r.x > DTH ? 1 : 0) | (r.y > DTH ? 2 : 0) |
              (r.z > DTH ? 4 : 0) | (r.w > DTH ? 8 : 0);
    int partner = __shfl_xor(nib, 1, 64);
    if ((threadIdx.x & 1) == 0)
        out_bits[(base + j) >> 3] = (float)(nib | (partner << 4));

    // block reduction of clip-sum
    #pragma unroll
    for (int off = 32; off; off >>= 1) lsum += __shfl_down(lsum, off, 64);
    __shared__ float wsum[16];
    if ((threadIdx.x & 63) == 0) wsum[threadIdx.x >> 6] = lsum;
    __syncthreads();
    if (threadIdx.x == 0) {
        float tot = 0.f;
        #pragma unroll
        for (int i = 0; i < 16; ++i) tot += wsum[i];
        partials[blk] = tot;
    }
}

__global__ __launch_bounds__(1024) void
reduce_thresh(const float* __restrict__ partials, float* __restrict__ thresh)
{
    float s = 0.f;
    for (int i = threadIdx.x; i < NBLK1; i += 1024) s += partials[i];
    #pragma unroll
    for (int off = 32; off; off >>= 1) s += __shfl_down(s, off, 64);
    __shared__ float wsum[16];
    if ((threadIdx.x & 63) == 0) wsum[threadIdx.x >> 6] = s;
    __syncthreads();
    if (threadIdx.x == 0) {
        float tot = 0.f;
        #pragma unroll
        for (int i = 0; i < 16; ++i) tot += wsum[i];
        thresh[0] = fminf(tot / (float)NTOT, DTH);
    }
}

// Fallback: only does work if mean < DTH (thresh != DTH). Early-exits otherwise.
__global__ __launch_bounds__(256) void
fix_bits(const float* __restrict__ grid, const float* __restrict__ thresh,
         float* __restrict__ out_bits)
{
    const float th = thresh[0];
    if (th == DTH) return;                       // common case: nothing to do
    const int n = blockIdx.x * 256 + threadIdx.x; // byte index < NBYTES_OUT
    const float4* g = reinterpret_cast<const float4*>(grid) + (n << 1);
    const float4 a = g[0], b = g[1];
    int byte = (a.x > th ? 1 : 0)   | (a.y > th ? 2 : 0)   |
               (a.z > th ? 4 : 0)   | (a.w > th ? 8 : 0)   |
               (b.x > th ? 16 : 0)  | (b.y > th ? 32 : 0)  |
               (b.z > th ? 64 : 0)  | (b.w > th ? 128 : 0);
    out_bits[n] = (float)byte;
}

extern "C" void kernel_launch(void* const* d_in, const int* in_sizes, int n_in,
                              void* d_out, int out_size, void* d_ws, size_t ws_size,
                              hipStream_t stream)
{
    const float* dg = (const float*)d_in[0];   // density_grid [T,1,G^3]
    const float* sg = (const float*)d_in[1];   // sigmas       [T,1,G^3]
    float* out_grid = (float*)d_out;           // [T,1,G^3]
    float* out_bits = out_grid + NTOT;         // [T, G^3/8] as float values
    float* partials = (float*)d_ws;            // NBLK1 floats
    float* thresh   = partials + NBLK1;        // 1 float

    pass1<<<NBLK1, 1024, 0, stream>>>(dg, sg, out_grid, out_bits, partials);
    reduce_thresh<<<1, 1024, 0, stream>>>(partials, thresh);
    fix_bits<<<NBYTES_OUT / 256, 256, 0, stream>>>(out_grid, thresh, out_bits);
}

// Round 2
// 178.324 us; speedup vs baseline: 1.1531x; 1.1531x over previous
//
#include <hip/hip_runtime.h>

#define G    128
#define G3   (G * G * G)          // 2097152
#define TDIM 32
#define NTOT (TDIM * G3)          // 67108864
#define NBYTES_OUT (NTOT / 8)     // 8388608
#define DECAY 0.95f
#define DTH   0.01f
#define NBLK1 (TDIM * 512)        // 16384 blocks, each = one (t, 16^3 cube)

// instant-ngp style bit expansion (good for <=10-bit inputs)
__device__ __forceinline__ unsigned expand3(unsigned v) {
    v = (v * 0x00010001u) & 0xFF0000FFu;
    v = (v * 0x00000101u) & 0x0F00F00Fu;
    v = (v * 0x00000011u) & 0xC30C30C3u;
    v = (v * 0x00000005u) & 0x49249249u;
    return v;
}

// extract every 3rd bit starting at bit 0
__device__ __forceinline__ unsigned compact3(unsigned v) {
    v &= 0x49249249u;
    v = (v | (v >> 2))  & 0xC30C30C3u;
    v = (v | (v >> 4))  & 0x0F00F00Fu;
    v = (v | (v >> 8))  & 0xFF0000FFu;
    v = (v | (v >> 16)) & 0x000003FFu;
    return v;
}

// Fused pass: per block = one (t, 16^3 cube).
// Phase A: coalesced linear read of sigma cube -> LDS in (swizzled) local-morton layout.
// Phase B: morton-order streaming: lds float4 + density float4 -> merge -> out float4 + bits.
__global__ __launch_bounds__(256) void
pass1(const float* __restrict__ dg, const float* __restrict__ sg,
      float* __restrict__ out_grid, float* __restrict__ out_bits,
      float* __restrict__ partials)
{
    __shared__ float smem[4096];          // 16 KB
    const int blk  = blockIdx.x;          // t*512 + cube_morton
    const int t    = blk >> 9;
    const int cube = blk & 511;
    const int base = t * G3;

    // cube origin in linear space (cube coords from 9-bit cube morton)
    const unsigned Xc = compact3((unsigned)cube);
    const unsigned Yc = compact3((unsigned)cube >> 1);
    const unsigned Zc = compact3((unsigned)cube >> 2);
    const int origin  = (int)((Xc << 18) | (Yc << 11) | (Zc << 4)); // (Xc*16)*16384+(Yc*16)*128+Zc*16
    const float* __restrict__ sgt = sg + base + origin;

    // ---- Phase A: linear -> LDS (morton layout, XOR-swizzled) ----
    #pragma unroll
    for (int k = 0; k < 4; ++k) {
        const int c  = threadIdx.x + (k << 8);      // 0..1023 chunk id
        const int lx = c >> 6;                      // [0,16)
        const int ly = (c >> 2) & 15;               // [0,16)
        const int lz = (c & 3) << 2;                // {0,4,8,12}
        const float4 s = *reinterpret_cast<const float4*>(sgt + (lx << 14) + (ly << 7) + lz);
        // local morton of (lx,ly,lz); lz has low 2 bits clear -> morton bits 2,5 clear
        const int m = (int)(expand3((unsigned)lx) | (expand3((unsigned)ly) << 1)
                          | (expand3((unsigned)lz) << 2));
        // swizzle: inject m bits 7,8,10 into bank bits 2,3,4 (preserves bits 0,1 -> b128 groups intact)
        const int x = (((m >> 7) & 1) << 2) ^ (((m >> 8) & 1) << 3) ^ (((m >> 10) & 1) << 4);
        smem[m ^ x]        = s.x;   // z+0
        smem[(m | 4) ^ x]  = s.y;   // z+1 (morton +4)
        smem[(m | 32) ^ x] = s.z;   // z+2 (morton +32)
        smem[(m | 36) ^ x] = s.w;   // z+3
    }
    __syncthreads();

    // ---- Phase B: morton-order streaming ----
    float lsum = 0.f;
    #pragma unroll
    for (int k = 0; k < 4; ++k) {
        const int j  = (threadIdx.x + (k << 8)) << 2;   // local morton, 4-aligned
        const int xb = (((j >> 7) & 1) << 2) ^ (((j >> 8) & 1) << 3) ^ (((j >> 10) & 1) << 4);
        const float4 s = *reinterpret_cast<const float4*>(&smem[j ^ xb]);

        const int jg = base + (cube << 12) + j;         // global flat index (morton order)
        const float4 v = *reinterpret_cast<const float4*>(dg + jg);

        float4 r;
        r.x = (v.x >= 0.f && s.x >= 0.f) ? fmaxf(v.x * DECAY, s.x) : v.x;
        r.y = (v.y >= 0.f && s.y >= 0.f) ? fmaxf(v.y * DECAY, s.y) : v.y;
        r.z = (v.z >= 0.f && s.z >= 0.f) ? fmaxf(v.z * DECAY, s.z) : v.z;
        r.w = (v.w >= 0.f && s.w >= 0.f) ? fmaxf(v.w * DECAY, s.w) : v.w;

        *reinterpret_cast<float4*>(out_grid + jg) = r;

        lsum += fmaxf(r.x, 0.f) + fmaxf(r.y, 0.f) + fmaxf(r.z, 0.f) + fmaxf(r.w, 0.f);

        // bitfield assuming thresh == DTH (fixed up later iff mean < DTH)
        int nib = (r.x > DTH ? 1 : 0) | (r.y > DTH ? 2 : 0) |
                  (r.z > DTH ? 4 : 0) | (r.w > DTH ? 8 : 0);
        int partner = __shfl_xor(nib, 1, 64);
        if ((threadIdx.x & 1) == 0)
            out_bits[jg >> 3] = (float)(nib | (partner << 4));
    }

    // block reduction of clip-sum (4 waves)
    #pragma unroll
    for (int off = 32; off; off >>= 1) lsum += __shfl_down(lsum, off, 64);
    __shared__ float wsum[4];
    if ((threadIdx.x & 63) == 0) wsum[threadIdx.x >> 6] = lsum;
    __syncthreads();
    if (threadIdx.x == 0)
        partials[blk] = wsum[0] + wsum[1] + wsum[2] + wsum[3];
}

__global__ __launch_bounds__(1024) void
reduce_thresh(const float* __restrict__ partials, float* __restrict__ thresh)
{
    float s = 0.f;
    for (int i = threadIdx.x; i < NBLK1; i += 1024) s += partials[i];
    #pragma unroll
    for (int off = 32; off; off >>= 1) s += __shfl_down(s, off, 64);
    __shared__ float wsum[16];
    if ((threadIdx.x & 63) == 0) wsum[threadIdx.x >> 6] = s;
    __syncthreads();
    if (threadIdx.x == 0) {
        float tot = 0.f;
        #pragma unroll
        for (int i = 0; i < 16; ++i) tot += wsum[i];
        thresh[0] = fminf(tot / (float)NTOT, DTH);
    }
}

// Fallback: only does work if mean < DTH (thresh != DTH). Early-exits otherwise.
__global__ __launch_bounds__(256) void
fix_bits(const float* __restrict__ grid, const float* __restrict__ thresh,
         float* __restrict__ out_bits)
{
    const float th = thresh[0];
    if (th == DTH) return;                        // common case: nothing to do
    const int n = blockIdx.x * 256 + threadIdx.x; // byte index < NBYTES_OUT
    const float4* g = reinterpret_cast<const float4*>(grid) + (n << 1);
    const float4 a = g[0], b = g[1];
    int byte = (a.x > th ? 1 : 0)   | (a.y > th ? 2 : 0)   |
               (a.z > th ? 4 : 0)   | (a.w > th ? 8 : 0)   |
               (b.x > th ? 16 : 0)  | (b.y > th ? 32 : 0)  |
               (b.z > th ? 64 : 0)  | (b.w > th ? 128 : 0);
    out_bits[n] = (float)byte;
}

extern "C" void kernel_launch(void* const* d_in, const int* in_sizes, int n_in,
                              void* d_out, int out_size, void* d_ws, size_t ws_size,
                              hipStream_t stream)
{
    const float* dg = (const float*)d_in[0];   // density_grid [T,1,G^3]
    const float* sg = (const float*)d_in[1];   // sigmas       [T,1,G^3]
    float* out_grid = (float*)d_out;           // [T,1,G^3]
    float* out_bits = out_grid + NTOT;         // [T, G^3/8] as float values
    float* partials = (float*)d_ws;            // NBLK1 floats
    float* thresh   = partials + NBLK1;        // 1 float

    pass1<<<NBLK1, 256, 0, stream>>>(dg, sg, out_grid, out_bits, partials);
    reduce_thresh<<<1, 1024, 0, stream>>>(partials, thresh);
    fix_bits<<<NBYTES_OUT / 256, 256, 0, stream>>>(out_grid, thresh, out_bits);
}